// Round 8
// baseline (758.852 us; speedup 1.0000x reference)
//
#include <hip/hip_runtime.h>
#include <math.h>

#define HID    1024
#define GG     64
#define KPROP  5
#define H1     512
#define H2     256
#define NCLS   40
#define BNEPS  1e-5f
#define TILE   2048
#define BPART  256     // partition blocks
#define NBINS  1024    // buckets of 128 nodes (supports n <= 131072)

__host__ __device__ static inline int cdiv(int a, int b) { return (a + b - 1) / b; }

// ---------- Pass A: per-block histogram of col>>7 ----------
__global__ __launch_bounds__(1024) void k_hista(const int* __restrict__ col,
                                                int* __restrict__ blockHist, int e) {
    __shared__ int h[NBINS];
    for (int i = threadIdx.x; i < NBINS; i += 1024) h[i] = 0;
    __syncthreads();
    int chunk = cdiv(e, gridDim.x);
    int s = blockIdx.x * chunk, t = min(e, s + chunk);
    for (int i = s + threadIdx.x; i < t; i += 1024) atomicAdd(&h[col[i] >> 7], 1);
    __syncthreads();
    for (int i = threadIdx.x; i < NBINS; i += 1024)
        blockHist[blockIdx.x * NBINS + i] = h[i];
}

// ---------- Pass B: per-(block,bucket) offsets + PADDED bucket layout ----------
// Bucket regions padded to multiples of 8 ints so gather's int4 pairs are aligned.
__global__ __launch_bounds__(1024) void k_scan(const int* __restrict__ blockHist,
                                               int* __restrict__ blockOff,
                                               int* __restrict__ bucketPS,
                                               int* __restrict__ bucketEnd, int e, int n) {
    __shared__ int tot[NBINS];
    __shared__ int ps[NBINS];
    int bin = threadIdx.x;
    int s = 0;
    for (int b = 0; b < BPART; b++) {
        int v = blockHist[b * NBINS + bin];
        blockOff[b * NBINS + bin] = s;   // coalesced (bin contiguous across threads)
        s += v;
    }
    tot[bin] = s;
    __syncthreads();
    if (bin == 0) {
        int acc = 0;
        for (int i = 0; i < NBINS; i++) { ps[i] = acc; acc += (tot[i] + 7) & ~7; }
    }
    __syncthreads();
    bucketPS[bin]  = ps[bin];
    bucketEnd[bin] = ps[bin] + tot[bin];
}

// ---------- Pass C: scatter packed edges into bucket-grouped order ----------
__global__ __launch_bounds__(1024) void k_scat(const int* __restrict__ row,
                                               const int* __restrict__ col,
                                               const int* __restrict__ blockOff,
                                               const int* __restrict__ bucketPS,
                                               int* __restrict__ ebuf, int e) {
    __shared__ int c2[NBINS];
    for (int i = threadIdx.x; i < NBINS; i += 1024) c2[i] = 0;
    __syncthreads();
    int chunk = cdiv(e, gridDim.x);
    int s = blockIdx.x * chunk, t = min(e, s + chunk);
    const int* boff = blockOff + blockIdx.x * NBINS;
    for (int i = s + threadIdx.x; i < t; i += 1024) {
        int c = col[i];
        int bin = c >> 7;
        int lr = atomicAdd(&c2[bin], 1);                 // LDS atomic — cheap
        int pos = bucketPS[bin] + boff[bin] + lr;        // globally unique
        ebuf[pos] = row[i] | ((c & 127) << 17);          // row<2^17, 7-bit local target
    }
}

// ---------- Pass D: per-bucket degree histogram + fused z0 init ----------
__global__ __launch_bounds__(256) void k_deg0(const int* __restrict__ bucketPS,
                                              const int* __restrict__ bucketEnd,
                                              const int* __restrict__ ebuf,
                                              int* __restrict__ deg,
                                              const float* __restrict__ pos,
                                              float4* __restrict__ z0, int n) {
    __shared__ int cnt[128];
    int g = blockIdx.x;
    if (threadIdx.x < 128) cnt[threadIdx.x] = 0;
    __syncthreads();
    int s0 = bucketPS[g], s1 = bucketEnd[g];
    for (int i = s0 + threadIdx.x; i < s1; i += 256)
        atomicAdd(&cnt[(ebuf[i] >> 17) & 127], 1);
    __syncthreads();
    int node = g * 128 + threadIdx.x;
    if (threadIdx.x < 128 && node < n) {
        int d = cnt[threadIdx.x];
        deg[node] = d;
        float dis = rsqrtf((float)(d + 1));
        z0[node] = make_float4(dis * pos[3 * node], dis * pos[3 * node + 1],
                               dis * pos[3 * node + 2], 0.f);
    }
}

// ---------- gather pass: edge-centric per bucket, LDS accumulate ----------
// 512 threads/block, one block per 128-node bucket (~4096 edges). Each thread:
// two coalesced int4 reads of packed edges, 8 independent z-gathers in flight,
// ds_add_f32 accumulate by local target. 6256 waves total (24/CU) at ILP-8 —
// ~4x R7's outstanding-request product.
template <bool FINAL>
__global__ __launch_bounds__(512) void k_gatherb(
    const int* __restrict__ ebuf, const int* __restrict__ bucketPS,
    const int* __restrict__ bucketEnd, const int* __restrict__ deg,
    const float4* __restrict__ zin, float4* __restrict__ zout,
    double* stats, int n) {
    __shared__ float ax[128], ay[128], az[128];
    int tid = threadIdx.x;
    if (tid < 128) { ax[tid] = 0.f; ay[tid] = 0.f; az[tid] = 0.f; }
    __syncthreads();
    int g = blockIdx.x;
    int s0 = bucketPS[g], s1 = bucketEnd[g];
    for (int j0 = s0 + tid * 8; j0 < s1; j0 += 512 * 8) {
        if (j0 + 8 <= s1) {
            int4 qa = *(const int4*)(ebuf + j0);       // aligned: s0 % 8 == 0
            int4 qb = *(const int4*)(ebuf + j0 + 4);
            float4 v0 = zin[qa.x & 0x1FFFF];
            float4 v1 = zin[qa.y & 0x1FFFF];
            float4 v2 = zin[qa.z & 0x1FFFF];
            float4 v3 = zin[qa.w & 0x1FFFF];
            float4 v4 = zin[qb.x & 0x1FFFF];
            float4 v5 = zin[qb.y & 0x1FFFF];
            float4 v6 = zin[qb.z & 0x1FFFF];
            float4 v7 = zin[qb.w & 0x1FFFF];
            int t0 = (qa.x >> 17) & 127, t1 = (qa.y >> 17) & 127;
            int t2 = (qa.z >> 17) & 127, t3 = (qa.w >> 17) & 127;
            int t4 = (qb.x >> 17) & 127, t5 = (qb.y >> 17) & 127;
            int t6 = (qb.z >> 17) & 127, t7 = (qb.w >> 17) & 127;
            atomicAdd(&ax[t0], v0.x); atomicAdd(&ay[t0], v0.y); atomicAdd(&az[t0], v0.z);
            atomicAdd(&ax[t1], v1.x); atomicAdd(&ay[t1], v1.y); atomicAdd(&az[t1], v1.z);
            atomicAdd(&ax[t2], v2.x); atomicAdd(&ay[t2], v2.y); atomicAdd(&az[t2], v2.z);
            atomicAdd(&ax[t3], v3.x); atomicAdd(&ay[t3], v3.y); atomicAdd(&az[t3], v3.z);
            atomicAdd(&ax[t4], v4.x); atomicAdd(&ay[t4], v4.y); atomicAdd(&az[t4], v4.z);
            atomicAdd(&ax[t5], v5.x); atomicAdd(&ay[t5], v5.y); atomicAdd(&az[t5], v5.z);
            atomicAdd(&ax[t6], v6.x); atomicAdd(&ay[t6], v6.y); atomicAdd(&az[t6], v6.z);
            atomicAdd(&ax[t7], v7.x); atomicAdd(&ay[t7], v7.y); atomicAdd(&az[t7], v7.z);
        } else {
            for (int j = j0; j < s1; j++) {
                int v = ebuf[j];
                float4 a = zin[v & 0x1FFFF];
                int tt = (v >> 17) & 127;
                atomicAdd(&ax[tt], a.x); atomicAdd(&ay[tt], a.y); atomicAdd(&az[tt], a.z);
            }
        }
    }
    __syncthreads();
    float x0 = 0.f, x1 = 0.f, x2 = 0.f;
    int node = g * 128 + tid;
    if (tid < 128 && node < n) {
        float4 zi = zin[node];                       // self loop
        float dg = (float)(deg[node] + 1);
        float sc = FINAL ? rsqrtf(dg) : (1.0f / dg);
        x0 = sc * (ax[tid] + zi.x);
        x1 = sc * (ay[tid] + zi.y);
        x2 = sc * (az[tid] + zi.z);
        zout[node] = make_float4(x0, x1, x2, 0.f);
    }
    if (FINAL && tid < 128) {                        // waves 0,1 only; zeros elsewhere
        double v[9];
        v[0] = x0; v[1] = x1; v[2] = x2;
        v[3] = (double)x0 * x0; v[4] = (double)x0 * x1; v[5] = (double)x0 * x2;
        v[6] = (double)x1 * x1; v[7] = (double)x1 * x2; v[8] = (double)x2 * x2;
#pragma unroll
        for (int jj = 0; jj < 9; jj++) {
            double t = v[jj];
            for (int m = 1; m < 64; m <<= 1) t += __shfl_xor(t, m, 64);
            if ((tid & 63) == 0) atomicAdd(&stats[jj], t);
        }
    }
}

// ---------- graph boundaries via binary search (batch is sorted) ----------
__global__ void k_bounds(const int* __restrict__ batch, int* starts, int n) {
    int g = threadIdx.x;
    if (g <= GG) {
        int lo = 0, hi = n;
        while (lo < hi) {
            int mid = (lo + hi) >> 1;
            if (batch[mid] < g) lo = mid + 1; else hi = mid;
        }
        starts[g] = lo;
    }
}

// ---------- pooling: per (graph, channel) max/min of dot(x, W_c), fused BN0+ReLU ----------
__global__ __launch_bounds__(256) void k_pool(
    const float4* __restrict__ z, const int* __restrict__ starts,
    const float* __restrict__ lin_w,
    const float* __restrict__ bn0_g, const float* __restrict__ bn0_b,
    const double* __restrict__ stats, float* pooled, int n) {
    __shared__ float4 sh[TILE];
    int g = blockIdx.x;
    int c = blockIdx.y * 256 + threadIdx.x;

    float w0 = lin_w[c], w1 = lin_w[HID + c], w2 = lin_w[2 * HID + c];

    double invN = 1.0 / (double)n;
    double mu0 = stats[0] * invN, mu1 = stats[1] * invN, mu2 = stats[2] * invN;
    float c00 = (float)(stats[3] * invN - mu0 * mu0);
    float c01 = (float)(stats[4] * invN - mu0 * mu1);
    float c02 = (float)(stats[5] * invN - mu0 * mu2);
    float c11 = (float)(stats[6] * invN - mu1 * mu1);
    float c12 = (float)(stats[7] * invN - mu1 * mu2);
    float c22 = (float)(stats[8] * invN - mu2 * mu2);
    float meanc = (float)mu0 * w0 + (float)mu1 * w1 + (float)mu2 * w2;  // lin_b cancels in BN
    float var = c00 * w0 * w0 + c11 * w1 * w1 + c22 * w2 * w2
              + 2.f * (c01 * w0 * w1 + c02 * w0 * w2 + c12 * w1 * w2);
    var = fmaxf(var, 0.f);

    int s0 = starts[g], s1 = starts[g + 1];
    float mx = -INFINITY, mn = INFINITY;
    for (int base = s0; base < s1; base += TILE) {
        int cnt = min(TILE, s1 - base);
        __syncthreads();
        for (int j = threadIdx.x; j < cnt; j += 256) sh[j] = z[base + j];
        __syncthreads();
        for (int j = 0; j < cnt; j++) {
            float4 p = sh[j];
            float d = fmaf(p.x, w0, fmaf(p.y, w1, p.z * w2));
            mx = fmaxf(mx, d);
            mn = fminf(mn, d);
        }
    }
    float inv = rsqrtf(var + BNEPS);
    float s = bn0_g[c] * inv;
    float raw = (s >= 0.f) ? mx : mn;     // BN scale sign decides which extreme survives relu∘max
    float y = (raw - meanc) * s + bn0_b[c];
    pooled[g * HID + c] = fmaxf(y, 0.f);
}

// ---------- fused Linear + BN(over 64 rows = 1 wave) + ReLU; 1 wave per output column ----------
template <int KIN>
__global__ __launch_bounds__(64) void k_fcbn(
    const float* __restrict__ in, const float* __restrict__ W,
    const float* __restrict__ bias, const float* __restrict__ gamma,
    const float* __restrict__ beta, float* out, int Cout) {
    int c = blockIdx.x;
    int r = threadIdx.x;  // 64 rows == wave size
    const float* rowp = in + r * KIN;
    float acc = 0.f;
#pragma unroll 8
    for (int k = 0; k < KIN; k++) acc = fmaf(rowp[k], W[k * Cout + c], acc);
    float y = acc + bias[c];
    float sum = y, sq = y * y;
    for (int m = 1; m < 64; m <<= 1) {
        sum += __shfl_xor(sum, m, 64);
        sq  += __shfl_xor(sq, m, 64);
    }
    float mean = sum * (1.f / 64.f);
    float var  = fmaxf(sq * (1.f / 64.f) - mean * mean, 0.f);
    float o = (y - mean) * rsqrtf(var + BNEPS) * gamma[c] + beta[c];
    out[r * Cout + c] = fmaxf(o, 0.f);
}

// ---------- fc3 + log_softmax; 1 wave per row ----------
__global__ __launch_bounds__(64) void k_out(
    const float* __restrict__ in, const float* __restrict__ W,
    const float* __restrict__ bias, float* out) {
    int r = blockIdx.x;
    int c = threadIdx.x;
    bool act = c < NCLS;
    float z = -INFINITY;
    if (act) {
        const float* rowp = in + r * H2;
        float acc = 0.f;
#pragma unroll 8
        for (int k = 0; k < H2; k++) acc = fmaf(rowp[k], W[k * NCLS + c], acc);
        z = acc + bias[c];
    }
    float mx = z;
    for (int m = 1; m < 64; m <<= 1) mx = fmaxf(mx, __shfl_xor(mx, m, 64));
    float ex = act ? expf(z - mx) : 0.f;
    float se = ex;
    for (int m = 1; m < 64; m <<= 1) se += __shfl_xor(se, m, 64);
    if (act) out[r * NCLS + c] = z - mx - logf(se);
}

extern "C" void kernel_launch(void* const* d_in, const int* in_sizes, int n_in,
                              void* d_out, int out_size, void* d_ws, size_t ws_size,
                              hipStream_t stream) {
    const float* pos   = (const float*)d_in[0];
    const int*   ei    = (const int*)d_in[1];   // [2,E]: rows at [0,E), cols at [E,2E)
    const int*   batch = (const int*)d_in[2];
    const float* lin_w = (const float*)d_in[3];
    // d_in[4] lin_b cancels in BN0 centering
    const float* bn0_g = (const float*)d_in[5];
    const float* bn0_b = (const float*)d_in[6];
    const float* fc1_w = (const float*)d_in[7];
    const float* fc1_b = (const float*)d_in[8];
    const float* bn1_g = (const float*)d_in[9];
    const float* bn1_b = (const float*)d_in[10];
    const float* fc2_w = (const float*)d_in[11];
    const float* fc2_b = (const float*)d_in[12];
    const float* bn2_g = (const float*)d_in[13];
    const float* bn2_b = (const float*)d_in[14];
    const float* fc3_w = (const float*)d_in[15];
    const float* fc3_b = (const float*)d_in[16];

    int n = in_sizes[0] / 3;
    int e = in_sizes[1] / 2;
    int nbuck = cdiv(n, 128);

    auto align256 = [](size_t x) { return (x + 255) & ~(size_t)255; };
    char* w = (char*)d_ws;
    int*    blockHist = (int*)w;    w += align256((size_t)BPART * NBINS * 4);
    int*    blockOff  = (int*)w;    w += align256((size_t)BPART * NBINS * 4);
    int*    bucketPS  = (int*)w;    w += align256(NBINS * 4);
    int*    bucketEnd = (int*)w;    w += align256(NBINS * 4);
    int*    deg       = (int*)w;    w += align256((size_t)n * 4);
    int*    ebuf      = (int*)w;    w += align256(((size_t)e + 8 * NBINS) * 4);
    float4* za        = (float4*)w; w += align256((size_t)n * 16);
    float4* zb        = (float4*)w; w += align256((size_t)n * 16);
    double* stats     = (double*)w; w += align256(9 * sizeof(double));
    int*    starts    = (int*)w;    w += align256((GG + 1) * 4);
    float*  pooled    = (float*)w;  w += align256((size_t)GG * HID * 4);
    float*  h1        = (float*)w;  w += align256((size_t)GG * H1 * 4);
    float*  h2        = (float*)w;  w += align256((size_t)GG * H2 * 4);

    (void)hipMemsetAsync(stats, 0, 9 * sizeof(double), stream);

    const int* erow = ei;
    const int* ecol = ei + e;

    k_hista<<<BPART, 1024, 0, stream>>>(ecol, blockHist, e);
    k_scan <<<1, NBINS, 0, stream>>>(blockHist, blockOff, bucketPS, bucketEnd, e, n);
    k_scat <<<BPART, 1024, 0, stream>>>(erow, ecol, blockOff, bucketPS, ebuf, e);
    k_deg0 <<<nbuck, 256, 0, stream>>>(bucketPS, bucketEnd, ebuf, deg, pos, za, n);

    // K=5 passes, double-buffered: za->zb->za->zb->za->zb (final in zb)
    k_gatherb<false><<<nbuck, 512, 0, stream>>>(ebuf, bucketPS, bucketEnd, deg, za, zb, stats, n);
    k_gatherb<false><<<nbuck, 512, 0, stream>>>(ebuf, bucketPS, bucketEnd, deg, zb, za, stats, n);
    k_gatherb<false><<<nbuck, 512, 0, stream>>>(ebuf, bucketPS, bucketEnd, deg, za, zb, stats, n);
    k_gatherb<false><<<nbuck, 512, 0, stream>>>(ebuf, bucketPS, bucketEnd, deg, zb, za, stats, n);
    k_gatherb<true ><<<nbuck, 512, 0, stream>>>(ebuf, bucketPS, bucketEnd, deg, za, zb, stats, n);

    k_bounds<<<1, 128, 0, stream>>>(batch, starts, n);
    k_pool<<<dim3(GG, HID / 256), 256, 0, stream>>>(zb, starts, lin_w, bn0_g, bn0_b, stats, pooled, n);
    k_fcbn<HID><<<H1, 64, 0, stream>>>(pooled, fc1_w, fc1_b, bn1_g, bn1_b, h1, H1);
    k_fcbn<H1><<<H2, 64, 0, stream>>>(h1, fc2_w, fc2_b, bn2_g, bn2_b, h2, H2);
    k_out<<<GG, 64, 0, stream>>>(h2, fc3_w, fc3_b, (float*)d_out);
}